// Round 3
// baseline (126.173 us; speedup 1.0000x reference)
//
#include <hip/hip_runtime.h>

// Each (B,S) element = 32 floats (exact 0.0/1.0), 128 B.
//   eint = idx1..8 (MSB-first), mant = idx9..12
//   shift = (eint + 129) & 255; val5 = shift<=4 ? (16|mant) >> (4-shift) : 0
//   out dword j (j=0..4) = bit (4-j) of val5 as float 0.0/1.0
//
// Round-3 scheme: fully dense contiguous reads. Each wave streams contiguous
// 8 KiB per k-slice group (lane reads uint4 at base + k*64 + lane). Needed
// dwords (0..15 of each element) land in even quads; quad_perm OR-butterfly
// assembles the 16-bit word there. Odd quads (upper 64 B halves) are dead
// weight read only for stream density. Output staged in LDS, coalesced uint4.

#define BIT(u) (((u) >> 23) & 1u)

__global__ __launch_bounds__(256) void spike_kernel(
    const uint4* __restrict__ in, uint4* __restrict__ out)
{
    __shared__ unsigned int obuf[5120];  // 1024 elements * 5 dwords = 20 KiB

    const int t    = threadIdx.x;
    const int lane = t & 63;
    const int w    = t >> 6;           // wave 0..3
    const int sub  = lane & 7;         // which uint4 of the element this lane holds
    const int g    = lane >> 3;        // element-within-k-slice (0..7)
    const size_t blk_u4 = (size_t)blockIdx.x * 8192;

    const bool active    = (sub < 4);
    const int  nib_shift = (3 - (sub & 3)) * 4;

#pragma unroll
    for (int m = 0; m < 4; ++m) {
        uint4 v[8];
#pragma unroll
        for (int k = 0; k < 8; ++k)
            v[k] = in[blk_u4 + (size_t)m * 2048 + w * 512 + k * 64 + lane];

#pragma unroll
        for (int k = 0; k < 8; ++k) {
            uint4 u = v[k];
            unsigned int nib = (BIT(u.x) << 3) | (BIT(u.y) << 2) |
                               (BIT(u.z) << 1) |  BIT(u.w);
            int V = (int)(nib << nib_shift);
            V |= __builtin_amdgcn_mov_dpp(V, 0xB1, 0xF, 0xF, true); // quad_perm [1,0,3,2]
            V |= __builtin_amdgcn_mov_dpp(V, 0x4E, 0xF, 0xF, true); // quad_perm [2,3,0,1]
            unsigned int Vu = (unsigned int)V;
            // even quads: Vu bit15=idx0 ... bit0=idx15
            unsigned int eint  = (Vu >> 7) & 0xFFu;  // idx1..8
            unsigned int mant  = (Vu >> 3) & 0xFu;   // idx9..12
            unsigned int shift = (eint + 129u) & 255u;
            unsigned int val5  = (shift <= 4u) ? ((16u | mant) >> (4u - shift)) : 0u;

            if (active) {
                int em = m * 256 + w * 64 + k * 8 + g;   // element within block
                unsigned int* ob = &obuf[em * 5];
                ob[sub] = (0u - ((val5 >> (4 - sub)) & 1u)) & 0x3f800000u;
                if (sub == 0)
                    ob[4] = (0u - (val5 & 1u)) & 0x3f800000u;
            }
        }
    }

    __syncthreads();

    const uint4* ob4 = (const uint4*)obuf;
    uint4* q = out + (size_t)blockIdx.x * 1280;
#pragma unroll
    for (int kk = 0; kk < 5; ++kk)
        q[kk * 256 + t] = ob4[kk * 256 + t];
}

extern "C" void kernel_launch(void* const* d_in, const int* in_sizes, int n_in,
                              void* d_out, int out_size, void* d_ws, size_t ws_size,
                              hipStream_t stream) {
    (void)n_in; (void)d_ws; (void)ws_size; (void)out_size;
    const uint4* in = (const uint4*)d_in[0];
    uint4* out = (uint4*)d_out;

    int n_elem = in_sizes[0] / 32;          // 4,194,304
    int grid   = n_elem / 1024;             // 4096 blocks, 1024 elements each
    spike_kernel<<<grid, 256, 0, stream>>>(in, out);
}

// Round 5
// 106.364 us; speedup vs baseline: 1.1862x; 1.1862x over previous
//
#include <hip/hip_runtime.h>

// Each (B,S) element = 32 floats (exact 0.0/1.0), 128 B.
//   eint = idx1..8 (MSB-first), mant = idx9..12
//   shift = (eint + 129) & 255; val5 = shift<=4 ? (16|mant) >> (4-shift) : 0
//   out dword j (j=0..4) = bit (4-j) of val5 as float 0.0/1.0
//
// Round-5 = Round-3 dense-stream structure + NON-TEMPORAL loads/stores,
// using clang ext_vector_type (HIP_vector_type is rejected by the builtin).

typedef unsigned int u32x4 __attribute__((ext_vector_type(4)));

#define BIT(u) (((u) >> 23) & 1u)

__global__ __launch_bounds__(256) void spike_kernel(
    const u32x4* __restrict__ in, u32x4* __restrict__ out)
{
    __shared__ unsigned int obuf[5120];  // 1024 elements * 5 dwords = 20 KiB

    const int t    = threadIdx.x;
    const int lane = t & 63;
    const int w    = t >> 6;           // wave 0..3
    const int sub  = lane & 7;         // which uint4 of the element this lane holds
    const int g    = lane >> 3;        // element-within-k-slice (0..7)
    const size_t blk_u4 = (size_t)blockIdx.x * 8192;

    const bool active    = (sub < 4);
    const int  nib_shift = (3 - (sub & 3)) * 4;

#pragma unroll
    for (int m = 0; m < 4; ++m) {
        u32x4 v[8];
#pragma unroll
        for (int k = 0; k < 8; ++k)
            v[k] = __builtin_nontemporal_load(
                       &in[blk_u4 + (size_t)m * 2048 + w * 512 + k * 64 + lane]);

#pragma unroll
        for (int k = 0; k < 8; ++k) {
            u32x4 u = v[k];
            unsigned int nib = (BIT(u.x) << 3) | (BIT(u.y) << 2) |
                               (BIT(u.z) << 1) |  BIT(u.w);
            int V = (int)(nib << nib_shift);
            V |= __builtin_amdgcn_mov_dpp(V, 0xB1, 0xF, 0xF, true); // quad_perm [1,0,3,2]
            V |= __builtin_amdgcn_mov_dpp(V, 0x4E, 0xF, 0xF, true); // quad_perm [2,3,0,1]
            unsigned int Vu = (unsigned int)V;
            // even quads: Vu bit15=idx0 ... bit0=idx15
            unsigned int eint  = (Vu >> 7) & 0xFFu;  // idx1..8
            unsigned int mant  = (Vu >> 3) & 0xFu;   // idx9..12
            unsigned int shift = (eint + 129u) & 255u;
            unsigned int val5  = (shift <= 4u) ? ((16u | mant) >> (4u - shift)) : 0u;

            if (active) {
                int em = m * 256 + w * 64 + k * 8 + g;   // element within block
                unsigned int* ob = &obuf[em * 5];
                ob[sub] = (0u - ((val5 >> (4 - sub)) & 1u)) & 0x3f800000u;
                if (sub == 0)
                    ob[4] = (0u - (val5 & 1u)) & 0x3f800000u;
            }
        }
    }

    __syncthreads();

    const u32x4* ob4 = (const u32x4*)obuf;
    u32x4* q = out + (size_t)blockIdx.x * 1280;
#pragma unroll
    for (int kk = 0; kk < 5; ++kk)
        __builtin_nontemporal_store(ob4[kk * 256 + t], &q[kk * 256 + t]);
}

extern "C" void kernel_launch(void* const* d_in, const int* in_sizes, int n_in,
                              void* d_out, int out_size, void* d_ws, size_t ws_size,
                              hipStream_t stream) {
    (void)n_in; (void)d_ws; (void)ws_size; (void)out_size;
    const u32x4* in = (const u32x4*)d_in[0];
    u32x4* out = (u32x4*)d_out;

    int n_elem = in_sizes[0] / 32;          // 4,194,304
    int grid   = n_elem / 1024;             // 4096 blocks, 1024 elements each
    spike_kernel<<<grid, 256, 0, stream>>>(in, out);
}

// Round 6
// 103.015 us; speedup vs baseline: 1.2248x; 1.0325x over previous
//
#include <hip/hip_runtime.h>

// Each (B,S) element = 32 floats (exact 0.0/1.0), 128 B. Needed dwords 1..12
// live entirely in the element's FIRST 64 B sector.
//   eint = idx1..8 (MSB-first), mant = idx9..12
//   shift = (eint + 129) & 255; val5 = shift<=4 ? (16|mant) >> (4-shift) : 0
//   out dword j (j=0..4) = bit (4-j) of val5 as float 0.0/1.0
//
// Round-6: probe NT fetch granularity. Load ONLY the first 64 B sector of
// each element (4 lanes/element, lane sub = t&3 -> 16 contiguous 64 B
// segments per wave instruction, stride 128), with non-temporal loads.
// If NT honors 64 B sectors, read traffic halves vs round-5.

typedef unsigned int u32x4 __attribute__((ext_vector_type(4)));

#define BIT(u) (((u) >> 23) & 1u)

__global__ __launch_bounds__(256) void spike_kernel(
    const u32x4* __restrict__ in, u32x4* __restrict__ out)
{
    __shared__ unsigned int obuf[5120];  // 1024 elements * 5 dwords = 20 KiB

    const int t   = threadIdx.x;
    const int sub = t & 3;     // which 16 B chunk of the element's first 64 B
    const int egq = t >> 2;    // element slot within an iteration
    const size_t blk_e0 = (size_t)blockIdx.x * 1024;

    const int nib_shift = (3 - sub) * 4;

#pragma unroll
    for (int i = 0; i < 16; ++i) {
        const int e_local = i * 64 + egq;
        u32x4 u = __builtin_nontemporal_load(&in[(blk_e0 + e_local) * 8 + sub]);

        unsigned int nib = (BIT(u.x) << 3) | (BIT(u.y) << 2) |
                           (BIT(u.z) << 1) |  BIT(u.w);
        int V = (int)(nib << nib_shift);
        V |= __builtin_amdgcn_mov_dpp(V, 0xB1, 0xF, 0xF, true); // quad_perm [1,0,3,2]
        V |= __builtin_amdgcn_mov_dpp(V, 0x4E, 0xF, 0xF, true); // quad_perm [2,3,0,1]
        unsigned int Vu = (unsigned int)V;
        // Vu: bit15=idx0 ... bit0=idx15
        unsigned int eint  = (Vu >> 7) & 0xFFu;  // idx1..8
        unsigned int mant  = (Vu >> 3) & 0xFu;   // idx9..12
        unsigned int shift = (eint + 129u) & 255u;
        unsigned int val5  = (shift <= 4u) ? ((16u | mant) >> (4u - shift)) : 0u;

        unsigned int* ob = &obuf[e_local * 5];
        ob[sub] = (0u - ((val5 >> (4 - sub)) & 1u)) & 0x3f800000u;
        if (sub == 0)
            ob[4] = (0u - (val5 & 1u)) & 0x3f800000u;
    }

    __syncthreads();

    const u32x4* ob4 = (const u32x4*)obuf;
    u32x4* q = out + (size_t)blockIdx.x * 1280;
#pragma unroll
    for (int kk = 0; kk < 5; ++kk)
        __builtin_nontemporal_store(ob4[kk * 256 + t], &q[kk * 256 + t]);
}

extern "C" void kernel_launch(void* const* d_in, const int* in_sizes, int n_in,
                              void* d_out, int out_size, void* d_ws, size_t ws_size,
                              hipStream_t stream) {
    (void)n_in; (void)d_ws; (void)ws_size; (void)out_size;
    const u32x4* in = (const u32x4*)d_in[0];
    u32x4* out = (u32x4*)d_out;

    int n_elem = in_sizes[0] / 32;          // 4,194,304
    int grid   = n_elem / 1024;             // 4096 blocks, 1024 elements each
    spike_kernel<<<grid, 256, 0, stream>>>(in, out);
}